// Round 6
// baseline (151.722 us; speedup 1.0000x reference)
//
#include <hip/hip_runtime.h>
#include <math.h>

#define N_EL    16
#define N_NUC   4
#define N_FEATS 32
#define N_PAIRS 184
#define HIDDEN  64
#define TB      32           // batch elements per block
#define BLOCK   256
#define DLD     185          // dist LDS stride
#define H1LD    68           // h1 stride
#define TPW     23           // K-tiles (2 pairs each) per wave; 4*23*2 = 184

typedef int   intx8    __attribute__((ext_vector_type(8)));
typedef float floatx16 __attribute__((ext_vector_type(16)));

// triu_indices(16, 1)
__constant__ unsigned char c_I[120] = {
    0,0,0,0,0,0,0,0,0,0,0,0,0,0,0,
    1,1,1,1,1,1,1,1,1,1,1,1,1,1,
    2,2,2,2,2,2,2,2,2,2,2,2,2,
    3,3,3,3,3,3,3,3,3,3,3,3,
    4,4,4,4,4,4,4,4,4,4,4,
    5,5,5,5,5,5,5,5,5,5,
    6,6,6,6,6,6,6,6,6,
    7,7,7,7,7,7,7,7,
    8,8,8,8,8,8,8,
    9,9,9,9,9,9,
    10,10,10,10,10,
    11,11,11,11,
    12,12,12,
    13,13,
    14
};
__constant__ unsigned char c_J[120] = {
    1,2,3,4,5,6,7,8,9,10,11,12,13,14,15,
    2,3,4,5,6,7,8,9,10,11,12,13,14,15,
    3,4,5,6,7,8,9,10,11,12,13,14,15,
    4,5,6,7,8,9,10,11,12,13,14,15,
    5,6,7,8,9,10,11,12,13,14,15,
    6,7,8,9,10,11,12,13,14,15,
    7,8,9,10,11,12,13,14,15,
    8,9,10,11,12,13,14,15,
    9,10,11,12,13,14,15,
    10,11,12,13,14,15,
    11,12,13,14,15,
    12,13,14,15,
    13,14,15,
    14,15,
    15
};

__device__ __forceinline__ float ssp(float x) {
    float a = fabsf(x);
    return fmaxf(x, 0.0f) + log1pf(__expf(-a)) - 0.69314718056f;
}
__device__ __forceinline__ float redg(float v) {
    v += __shfl_xor(v, 1);
    v += __shfl_xor(v, 2);
    v += __shfl_xor(v, 4);
    return v;
}

// ---------------------------------------------------------------------------
// Prep (verified R14): W1 -> fp8 e4m3 (pre-scaled 2^6; MFMA applies 2^-6 via
// scale_b) in 32x32x64 B-fragment order.
// ---------------------------------------------------------------------------
__global__ __launch_bounds__(256)
void prep_w1_kernel(const float* __restrict__ W1, intx8* __restrict__ ws)
{
    __shared__ float w[2 * N_FEATS * HIDDEN];   // 16 KB: two pairs' rows
    const int t = blockIdx.x;
    const float* src = W1 + (size_t)(2 * t) * (N_FEATS * HIDDEN);
    for (int k = threadIdx.x; k < 2 * N_FEATS * HIDDEN; k += 256) w[k] = src[k];
    __syncthreads();

    const int tid = threadIdx.x;
    if (tid >= 128) return;
    const int lane = tid & 63;
    const int nh   = tid >> 6;
    const int lh   = lane >> 5;
    const int col  = nh * 32 + (lane & 31);
    const int fb   = lh * 16;
    intx8 frag;
#pragma unroll
    for (int r = 0; r < 8; ++r) {
        const int pair = r >> 2;
        const int fo   = fb + ((r & 3) << 2);
        const float v0 = 64.0f * w[(pair * N_FEATS + fo + 0) * 64 + col];
        const float v1 = 64.0f * w[(pair * N_FEATS + fo + 1) * 64 + col];
        const float v2 = 64.0f * w[(pair * N_FEATS + fo + 2) * 64 + col];
        const float v3 = 64.0f * w[(pair * N_FEATS + fo + 3) * 64 + col];
        int d = __builtin_amdgcn_cvt_pk_fp8_f32(v0, v1, 0, false);
        d     = __builtin_amdgcn_cvt_pk_fp8_f32(v2, v3, d, true);
        frag[r] = d;
    }
    ws[(size_t)(t * 2 + nh) * 64 + lane] = frag;
}

// ---------------------------------------------------------------------------
// R21 — FUSED kernel. R19 gemm (verified, 129.1 us total) + in-LDS cross-wave
// reduction + tail, eliminating the 32 MB partials write + 33 MB read + tail
// launch + duplicate rs staging/asy dists (~12-15 us structural saving).
// Reduction: wave 0 plain-writes C partial to red[2048] (8 KB, aliased over
// dead lds_dist); barrier; waves 1-3 atomicAdd (ds_add_f32); barrier; each
// thread owns one column x 8 rows -> h1 = ssp(sum + b1); barrier; verified
// tail layers 2/3 + asy on the still-resident lds_rs.
// W2 is global-loaded to 4xfloat4 regs right after the K-loop and ds-written
// into the dist-aliased region after the post-K barrier.
// LDS: rs 6 KB + union(dist 23.7 | red 8 + w2 16 + h1 8.7 = 33.3) = 39.4 KB.
// ---------------------------------------------------------------------------
__global__ __launch_bounds__(BLOCK)
void wfnet_fused(const float* __restrict__ rs,
                 const float* __restrict__ coords,
                 const float* __restrict__ charges,
                 const intx8* __restrict__ ws,
                 const float* __restrict__ b1,
                 const float* __restrict__ W2,
                 const float* __restrict__ b2,
                 const float* __restrict__ W3,
                 const float* __restrict__ b3,
                 float* __restrict__ out)
{
    __shared__ float lds_rs[TB * N_EL * 3];        // 6 KB, live whole kernel
    __shared__ __align__(16) char lds_u[33280];    // union region
    float* lds_dist = (float*)lds_u;               // [TB*DLD] 23.7 KB (phase 2..K)
    float* red      = (float*)lds_u;               // [2048]   8 KB   (post-K)
    float* w2s      = (float*)(lds_u + 8192);      // [4096]  16 KB   (post-K)
    float* h1s      = (float*)(lds_u + 24576);     // [TB*H1LD] 8.5 KB(post-K)

    const int tid  = threadIdx.x;
    const int wave = tid >> 6;               // = kh
    const int lane = tid & 63;
    const int m    = lane & 31;
    const int lh   = lane >> 5;

    // ---- phase 1: stage rs ----
    {
        const float* rs_blk = rs + (size_t)blockIdx.x * (TB * N_EL * 3);
        for (int k = tid; k < TB * N_EL * 3; k += BLOCK) lds_rs[k] = rs_blk[k];
    }
    __syncthreads();

    // ---- phase 2: distances ----
    {
        const int bl = tid >> 3, g = tid & 7;
        const float* myrs = lds_rs + bl * (N_EL * 3);
        float* dst = lds_dist + bl * DLD;
        for (int i = 0; i < 8; ++i) {
            const int p = g + 8 * i;
            const int e = p >> 2, n = p & 3;
            const float dx = myrs[e * 3 + 0] - coords[n * 3 + 0];
            const float dy = myrs[e * 3 + 1] - coords[n * 3 + 1];
            const float dz = myrs[e * 3 + 2] - coords[n * 3 + 2];
            dst[p] = sqrtf(dx * dx + dy * dy + dz * dz);
        }
        for (int i = 0; i < 15; ++i) {
            const int q  = g + 8 * i;
            const int ei = 3 * (int)c_I[q], ej = 3 * (int)c_J[q];
            const float dx = myrs[ei + 0] - myrs[ej + 0];
            const float dy = myrs[ei + 1] - myrs[ej + 1];
            const float dz = myrs[ei + 2] - myrs[ej + 2];
            dst[64 + q] = sqrtf(dx * dx + dy * dy + dz * dz);
        }
    }
    __syncthreads();

    // per-lane Gaussian constants for feats lh*16 .. lh*16+15
    // P1 = sqrt(8*log2 e)/sigma; byte = sat_u8(56.5 - (d*P1+P0)^2)
    const int f0 = lh * 16;
#define MKC(P, FF) float P##1, P##0; { \
    const float fq = (float)(FF) * (1.0f / 31.0f); \
    const float mu = 10.0f * fq * fq; \
    const float is = 7.0f / (1.0f + 10.0f * fq); \
    P##1 = is * 3.3972871404442143f; \
    P##0 = -mu * P##1; }
    MKC(F0_,  f0 + 0)  MKC(F1_,  f0 + 1)  MKC(F2_,  f0 + 2)  MKC(F3_,  f0 + 3)
    MKC(F4_,  f0 + 4)  MKC(F5_,  f0 + 5)  MKC(F6_,  f0 + 6)  MKC(F7_,  f0 + 7)
    MKC(F8_,  f0 + 8)  MKC(F9_,  f0 + 9)  MKC(F10_, f0 + 10) MKC(F11_, f0 + 11)
    MKC(F12_, f0 + 12) MKC(F13_, f0 + 13) MKC(F14_, f0 + 14) MKC(F15_, f0 + 15)
#undef MKC

    floatx16 accA = {};
    floatx16 accB = {};
    const intx8* wq = ws + ((size_t)(wave * TPW) * 128 + lane);
    const float* drow = lds_dist + m * DLD + wave * (2 * TPW);

#define XZ(dd, P) ({ const float t_ = fmaf(dd, P##1, P##0); fmaf(t_, -t_, 56.5f); })
#define PKD(dd, A, B, C, D) ({ \
    unsigned w_; \
    w_ = __builtin_amdgcn_cvt_pk_u8_f32(XZ(dd, A), 0, 0u); \
    w_ = __builtin_amdgcn_cvt_pk_u8_f32(XZ(dd, B), 1, w_); \
    w_ = __builtin_amdgcn_cvt_pk_u8_f32(XZ(dd, C), 2, w_); \
    w_ = __builtin_amdgcn_cvt_pk_u8_f32(XZ(dd, D), 3, w_); \
    (int)w_; })
#define MKA8(AV, dx0, dx1) \
    intx8 AV; { \
    AV[0] = PKD(dx0, F0_,  F1_,  F2_,  F3_);  \
    AV[1] = PKD(dx0, F4_,  F5_,  F6_,  F7_);  \
    AV[2] = PKD(dx0, F8_,  F9_,  F10_, F11_); \
    AV[3] = PKD(dx0, F12_, F13_, F14_, F15_); \
    AV[4] = PKD(dx1, F0_,  F1_,  F2_,  F3_);  \
    AV[5] = PKD(dx1, F4_,  F5_,  F6_,  F7_);  \
    AV[6] = PKD(dx1, F8_,  F9_,  F10_, F11_); \
    AV[7] = PKD(dx1, F12_, F13_, F14_, F15_); }
#define KROUND(AV, Q0, Q1) { \
    accA = __builtin_amdgcn_mfma_scale_f32_32x32x64_f8f6f4( \
               AV, Q0, accA, 0, 0, 0, 0x7F7F7F7F, 0, 0x79797979); \
    accB = __builtin_amdgcn_mfma_scale_f32_32x32x64_f8f6f4( \
               AV, Q1, accB, 0, 0, 0, 0x7F7F7F7F, 0, 0x79797979); }

    intx8 pA0 = wq[0],   pA1 = wq[64];
    intx8 pB0 = wq[128], pB1 = wq[192];
    float dA0 = drow[0], dA1 = drow[1];
    float dB0 = drow[2], dB1 = drow[3];

    for (int it = 0; it < 10; ++it) {
        const intx8* wn = wq + 256;
        const float eA0 = drow[4 * it + 4], eA1 = drow[4 * it + 5];
        const float eB0 = drow[4 * it + 6], eB1 = drow[4 * it + 7];

        { MKA8(av, dA0, dA1) KROUND(av, pA0, pA1) }
        pA0 = wn[0]; pA1 = wn[64];

        { MKA8(bv, dB0, dB1) KROUND(bv, pB0, pB1) }
        pB0 = wn[128]; pB1 = wn[192];

        wq = wn;
        dA0 = eA0; dA1 = eA1; dB0 = eB0; dB1 = eB1;
    }
    {
        const intx8* wn = wq + 256;
        const float eA0 = drow[44], eA1 = drow[45];
        { MKA8(av, dA0, dA1) KROUND(av, pA0, pA1) }
        pA0 = wn[0]; pA1 = wn[64];
        { MKA8(bv, dB0, dB1) KROUND(bv, pB0, pB1) }
        { MKA8(cv, eA0, eA1) KROUND(cv, pA0, pA1) }
    }
#undef KROUND
#undef MKA8
#undef PKD
#undef XZ

    // ---- issue W2 global loads now; HBM/L2 latency hides under the barrier
    //      and reduction phases; ds_write after the aliasing barrier ----
    const float4* W2g = (const float4*)W2;
    const float4 w2r0 = W2g[tid];
    const float4 w2r1 = W2g[tid + 256];
    const float4 w2r2 = W2g[tid + 512];
    const float4 w2r3 = W2g[tid + 768];

    __syncthreads();   // all waves done reading lds_dist; union region reusable

    // ---- 5a: wave 0 plain-writes its partial; all threads stage W2 ----
    if (wave == 0) {
#pragma unroll
        for (int rg = 0; rg < 16; ++rg) {
            const int el = (rg & 3) + 8 * (rg >> 2) + 4 * lh;
            red[el * 64 + m]      = accA[rg];
            red[el * 64 + 32 + m] = accB[rg];
        }
    }
    {
        float4* w2v = (float4*)w2s;
        w2v[tid]       = w2r0;
        w2v[tid + 256] = w2r1;
        w2v[tid + 512] = w2r2;
        w2v[tid + 768] = w2r3;
    }
    __syncthreads();   // wave 0's base values visible

    // ---- 5b: waves 1-3 accumulate via LDS atomics ----
    if (wave != 0) {
#pragma unroll
        for (int rg = 0; rg < 16; ++rg) {
            const int el = (rg & 3) + 8 * (rg >> 2) + 4 * lh;
            atomicAdd(&red[el * 64 + m],      accA[rg]);
            atomicAdd(&red[el * 64 + 32 + m], accB[rg]);
        }
    }
    __syncthreads();   // sums final

    // ---- 6: h1 = ssp(sum + b1). thread owns col c = tid&63, rows
    //         el = (tid>>6) + 4k. strided scalar LDS: conflict-free ----
    {
        const float b1c = b1[tid & 63];
#pragma unroll
        for (int k = 0; k < 8; ++k) {
            const int idx = tid + 256 * k;
            const int el  = idx >> 6;
            const int c   = tid & 63;
            h1s[el * H1LD + c] = ssp(red[idx] + b1c);
        }
    }

    // asy partial: thread's 8 el-nuc pairs (lds_rs still resident)
    const int el2 = tid >> 3;                // 0..31
    const int g2  = tid & 7;
    float asy = 0.0f;
    {
        const float* myrs = lds_rs + el2 * (N_EL * 3);
        const float4 ch = *(const float4*)charges;
#pragma unroll
        for (int i = 0; i < 8; ++i) {
            const int p = g2 + 8 * i;
            const int e = p >> 2, n = p & 3;
            const float dx = myrs[e * 3 + 0] - coords[n * 3 + 0];
            const float dy = myrs[e * 3 + 1] - coords[n * 3 + 1];
            const float dz = myrs[e * 3 + 2] - coords[n * 3 + 2];
            const float d = sqrtf(dx * dx + dy * dy + dz * dz);
            const float Z = (n < 2) ? ((n == 0) ? ch.x : ch.y)
                                    : ((n == 2) ? ch.z : ch.w);
            asy += (Z * d + d * d) / (1.0f + d);   // decay = sqrt(2*0.5) = 1
        }
    }
    asy = redg(asy);
    __syncthreads();   // h1 fully written

    // ---- 7: layers 2/3 (W2 from LDS), output ----
    const float4* __restrict__ W2v = (const float4*)w2s;
    const float4* __restrict__ b2v = (const float4*)b2;
    const int wbi = g2 * 2;
    const float4 b2a = b2v[wbi], b2b = b2v[wbi + 1];
    float s0 = b2a.x, s1 = b2a.y, s2 = b2a.z, s3 = b2a.w;
    float s4 = b2b.x, s5 = b2b.y, s6 = b2b.z, s7 = b2b.w;

    const float* __restrict__ h1row = h1s + el2 * H1LD;
    for (int k = 0; k < HIDDEN; ++k) {
        const float hk  = h1row[k];
        const float4 wa = W2v[k * 16 + wbi];
        const float4 wb = W2v[k * 16 + wbi + 1];
        s0 = fmaf(hk, wa.x, s0); s1 = fmaf(hk, wa.y, s1);
        s2 = fmaf(hk, wa.z, s2); s3 = fmaf(hk, wa.w, s3);
        s4 = fmaf(hk, wb.x, s4); s5 = fmaf(hk, wb.y, s5);
        s6 = fmaf(hk, wb.z, s6); s7 = fmaf(hk, wb.w, s7);
    }

    const float4* __restrict__ W3v = (const float4*)W3;
    const float4 w3a = W3v[wbi], w3b = W3v[wbi + 1];
    float part = ssp(s0) * w3a.x + ssp(s1) * w3a.y
               + ssp(s2) * w3a.z + ssp(s3) * w3a.w
               + ssp(s4) * w3b.x + ssp(s5) * w3b.y
               + ssp(s6) * w3b.z + ssp(s7) * w3b.w;
    part = redg(part);

    if (g2 == 0) {
        const float ys = part + b3[0];
        out[blockIdx.x * TB + el2] = __expf(ys) * __expf(-asy);
    }
}

extern "C" void kernel_launch(void* const* d_in, const int* in_sizes, int n_in,
                              void* d_out, int out_size, void* d_ws, size_t ws_size,
                              hipStream_t stream) {
    const float* rs      = (const float*)d_in[0];
    const float* coords  = (const float*)d_in[1];
    const float* charges = (const float*)d_in[2];
    const float* W1      = (const float*)d_in[3];
    const float* b1      = (const float*)d_in[4];
    const float* W2      = (const float*)d_in[5];
    const float* b2      = (const float*)d_in[6];
    const float* W3      = (const float*)d_in[7];
    const float* b3      = (const float*)d_in[8];
    float* out = (float*)d_out;

    const int batch = in_sizes[0] / (N_EL * 3);   // 32768
    intx8* w1f8     = (intx8*)d_ws;               // 368 KB fp8 W1

    prep_w1_kernel<<<N_PAIRS / 2, 256, 0, stream>>>(W1, w1f8);
    wfnet_fused<<<batch / TB, BLOCK, 0, stream>>>(rs, coords, charges, w1f8,
                                                  b1, W2, b2, W3, b3, out);
}

// Round 7
// 144.758 us; speedup vs baseline: 1.0481x; 1.0481x over previous
//
#include <hip/hip_runtime.h>
#include <math.h>

#define N_EL    16
#define N_NUC   4
#define N_FEATS 32
#define N_PAIRS 184
#define HIDDEN  64
#define TB      32           // batch elements per block
#define BLOCK   256
#define DLD     185          // dist LDS stride
#define H1LD    68           // h1 stride in kernel 2
#define TPW     23           // K-tiles (2 pairs each) per wave; 4*23*2 = 184
#define WS_PART_OFF (1 << 19)   // partials start at 512 KB into d_ws

typedef int   intx8    __attribute__((ext_vector_type(8)));
typedef float floatx16 __attribute__((ext_vector_type(16)));

// triu_indices(16, 1)
__constant__ unsigned char c_I[120] = {
    0,0,0,0,0,0,0,0,0,0,0,0,0,0,0,
    1,1,1,1,1,1,1,1,1,1,1,1,1,1,
    2,2,2,2,2,2,2,2,2,2,2,2,2,
    3,3,3,3,3,3,3,3,3,3,3,3,
    4,4,4,4,4,4,4,4,4,4,4,
    5,5,5,5,5,5,5,5,5,5,
    6,6,6,6,6,6,6,6,6,
    7,7,7,7,7,7,7,7,
    8,8,8,8,8,8,8,
    9,9,9,9,9,9,
    10,10,10,10,10,
    11,11,11,11,
    12,12,12,
    13,13,
    14
};
__constant__ unsigned char c_J[120] = {
    1,2,3,4,5,6,7,8,9,10,11,12,13,14,15,
    2,3,4,5,6,7,8,9,10,11,12,13,14,15,
    3,4,5,6,7,8,9,10,11,12,13,14,15,
    4,5,6,7,8,9,10,11,12,13,14,15,
    5,6,7,8,9,10,11,12,13,14,15,
    6,7,8,9,10,11,12,13,14,15,
    7,8,9,10,11,12,13,14,15,
    8,9,10,11,12,13,14,15,
    9,10,11,12,13,14,15,
    10,11,12,13,14,15,
    11,12,13,14,15,
    12,13,14,15,
    13,14,15,
    14,15,
    15
};

__device__ __forceinline__ float ssp(float x) {
    float a = fabsf(x);
    return fmaxf(x, 0.0f) + log1pf(__expf(-a)) - 0.69314718056f;
}
__device__ __forceinline__ float redg(float v) {
    v += __shfl_xor(v, 1);
    v += __shfl_xor(v, 2);
    v += __shfl_xor(v, 4);
    return v;
}

// ---------------------------------------------------------------------------
// Prep (verified R14): W1 -> fp8 e4m3 (pre-scaled 2^6; MFMA applies 2^-6 via
// scale_b) in 32x32x64 B-fragment order.
// ---------------------------------------------------------------------------
__global__ __launch_bounds__(256)
void prep_w1_kernel(const float* __restrict__ W1, intx8* __restrict__ ws)
{
    __shared__ float w[2 * N_FEATS * HIDDEN];   // 16 KB: two pairs' rows
    const int t = blockIdx.x;
    const float* src = W1 + (size_t)(2 * t) * (N_FEATS * HIDDEN);
    for (int k = threadIdx.x; k < 2 * N_FEATS * HIDDEN; k += 256) w[k] = src[k];
    __syncthreads();

    const int tid = threadIdx.x;
    if (tid >= 128) return;
    const int lane = tid & 63;
    const int nh   = tid >> 6;
    const int lh   = lane >> 5;
    const int col  = nh * 32 + (lane & 31);
    const int fb   = lh * 16;
    intx8 frag;
#pragma unroll
    for (int r = 0; r < 8; ++r) {
        const int pair = r >> 2;
        const int fo   = fb + ((r & 3) << 2);
        const float v0 = 64.0f * w[(pair * N_FEATS + fo + 0) * 64 + col];
        const float v1 = 64.0f * w[(pair * N_FEATS + fo + 1) * 64 + col];
        const float v2 = 64.0f * w[(pair * N_FEATS + fo + 2) * 64 + col];
        const float v3 = 64.0f * w[(pair * N_FEATS + fo + 3) * 64 + col];
        int d = __builtin_amdgcn_cvt_pk_fp8_f32(v0, v1, 0, false);
        d     = __builtin_amdgcn_cvt_pk_fp8_f32(v2, v3, d, true);
        frag[r] = d;
    }
    ws[(size_t)(t * 2 + nh) * 64 + lane] = frag;
}

// ---------------------------------------------------------------------------
// Kernel 1 — GEMM (R19 structure, verified absmax 0 @ 129.1 us total).
// R22: 2-deep software pipeline on the wq (fp8 W1) loads. R21's fused run
// proved gemm is stall-bound (HBM 0.5% peak, VALU 33%, MFMA 9%): 4 lockstep
// waves/SIMD all stall at the same marginal-slack L2 load. Holding {current,
// next} tile regs and prefetching it+2 raises load->use slack ~200 -> ~450 cy.
// +36 VGPR (~104); __launch_bounds__(256,4) keeps 4 blocks/CU resident.
// it=9 prefetch over-reads <=8 KB past the 368 KB W1 image into the ws pad
// below WS_PART_OFF (allocated, values unused).
// ---------------------------------------------------------------------------
__global__ __launch_bounds__(BLOCK, 4)
void wfnet_gemm(const float* __restrict__ rs,
                const float* __restrict__ coords,
                const intx8* __restrict__ ws,
                float* __restrict__ partials)
{
    __shared__ float lds_rs[TB * N_EL * 3];   // 6 KB
    __shared__ float lds_dist[TB * DLD];      // 23.7 KB

    const int tid  = threadIdx.x;
    const int wave = tid >> 6;               // = kh
    const int lane = tid & 63;
    const int m    = lane & 31;
    const int lh   = lane >> 5;

    // ---- phase 1: stage rs ----
    {
        const float* rs_blk = rs + (size_t)blockIdx.x * (TB * N_EL * 3);
        for (int k = tid; k < TB * N_EL * 3; k += BLOCK) lds_rs[k] = rs_blk[k];
    }
    __syncthreads();

    // ---- phase 2: distances only ----
    {
        const int bl = tid >> 3, g = tid & 7;
        const float* myrs = lds_rs + bl * (N_EL * 3);
        float* dst = lds_dist + bl * DLD;
        for (int i = 0; i < 8; ++i) {
            const int p = g + 8 * i;
            const int e = p >> 2, n = p & 3;
            const float dx = myrs[e * 3 + 0] - coords[n * 3 + 0];
            const float dy = myrs[e * 3 + 1] - coords[n * 3 + 1];
            const float dz = myrs[e * 3 + 2] - coords[n * 3 + 2];
            dst[p] = sqrtf(dx * dx + dy * dy + dz * dz);
        }
        for (int i = 0; i < 15; ++i) {
            const int q  = g + 8 * i;
            const int ei = 3 * (int)c_I[q], ej = 3 * (int)c_J[q];
            const float dx = myrs[ei + 0] - myrs[ej + 0];
            const float dy = myrs[ei + 1] - myrs[ej + 1];
            const float dz = myrs[ei + 2] - myrs[ej + 2];
            dst[64 + q] = sqrtf(dx * dx + dy * dy + dz * dz);
        }
    }
    __syncthreads();

    // per-lane Gaussian constants for feats lh*16 .. lh*16+15
    // P1 = sqrt(8*log2 e)/sigma; byte = sat_u8(56.5 - (d*P1+P0)^2)
    const int f0 = lh * 16;
#define MKC(P, FF) float P##1, P##0; { \
    const float fq = (float)(FF) * (1.0f / 31.0f); \
    const float mu = 10.0f * fq * fq; \
    const float is = 7.0f / (1.0f + 10.0f * fq); \
    P##1 = is * 3.3972871404442143f; \
    P##0 = -mu * P##1; }
    MKC(F0_,  f0 + 0)  MKC(F1_,  f0 + 1)  MKC(F2_,  f0 + 2)  MKC(F3_,  f0 + 3)
    MKC(F4_,  f0 + 4)  MKC(F5_,  f0 + 5)  MKC(F6_,  f0 + 6)  MKC(F7_,  f0 + 7)
    MKC(F8_,  f0 + 8)  MKC(F9_,  f0 + 9)  MKC(F10_, f0 + 10) MKC(F11_, f0 + 11)
    MKC(F12_, f0 + 12) MKC(F13_, f0 + 13) MKC(F14_, f0 + 14) MKC(F15_, f0 + 15)
#undef MKC

    floatx16 accA = {};
    floatx16 accB = {};
    const intx8* wq = ws + ((size_t)(wave * TPW) * 128 + lane);
    const float* drow = lds_dist + m * DLD + wave * (2 * TPW);

    // z = 56.5 - t^2 (>=0 only near the Gaussian center; cvt clamps the rest)
#define XZ(dd, P) ({ const float t_ = fmaf(dd, P##1, P##0); fmaf(t_, -t_, 56.5f); })
#define PKD(dd, A, B, C, D) ({ \
    unsigned w_; \
    w_ = __builtin_amdgcn_cvt_pk_u8_f32(XZ(dd, A), 0, 0u); \
    w_ = __builtin_amdgcn_cvt_pk_u8_f32(XZ(dd, B), 1, w_); \
    w_ = __builtin_amdgcn_cvt_pk_u8_f32(XZ(dd, C), 2, w_); \
    w_ = __builtin_amdgcn_cvt_pk_u8_f32(XZ(dd, D), 3, w_); \
    (int)w_; })
#define MKA8(AV, dx0, dx1) \
    intx8 AV; { \
    AV[0] = PKD(dx0, F0_,  F1_,  F2_,  F3_);  \
    AV[1] = PKD(dx0, F4_,  F5_,  F6_,  F7_);  \
    AV[2] = PKD(dx0, F8_,  F9_,  F10_, F11_); \
    AV[3] = PKD(dx0, F12_, F13_, F14_, F15_); \
    AV[4] = PKD(dx1, F0_,  F1_,  F2_,  F3_);  \
    AV[5] = PKD(dx1, F4_,  F5_,  F6_,  F7_);  \
    AV[6] = PKD(dx1, F8_,  F9_,  F10_, F11_); \
    AV[7] = PKD(dx1, F12_, F13_, F14_, F15_); }
#define KROUND(AV, Q0, Q1) { \
    accA = __builtin_amdgcn_mfma_scale_f32_32x32x64_f8f6f4( \
               AV, Q0, accA, 0, 0, 0, 0x7F7F7F7F, 0, 0x79797979); \
    accB = __builtin_amdgcn_mfma_scale_f32_32x32x64_f8f6f4( \
               AV, Q1, accB, 0, 0, 0, 0x7F7F7F7F, 0, 0x79797979); }

    // 2-deep pipeline: p* = tiles (2it, 2it+1); q* = tiles (2it+2, 2it+3)
    intx8 pA0 = wq[0],   pA1 = wq[64];
    intx8 pB0 = wq[128], pB1 = wq[192];
    intx8 qA0 = wq[256], qA1 = wq[320];
    intx8 qB0 = wq[384], qB1 = wq[448];
    float dA0 = drow[0], dA1 = drow[1];
    float dB0 = drow[2], dB1 = drow[3];
    float eA0 = drow[4], eA1 = drow[5];
    float eB0 = drow[6], eB1 = drow[7];

    for (int it = 0; it < 10; ++it) {
        const intx8* wf = wq + 512;                        // tiles 2it+4,2it+5
        const int dfA = 4 * it + 8;                        // <=44: in-bounds
        const int dfB = (it < 9) ? (4 * it + 10) : 40;     // clamp (unused @9)
        const float fA0 = drow[dfA],     fA1 = drow[dfA + 1];
        const float fB0 = drow[dfB],     fB1 = drow[dfB + 1];

        { MKA8(av, dA0, dA1) KROUND(av, pA0, pA1) }
        pA0 = qA0; pA1 = qA1; qA0 = wf[0]; qA1 = wf[64];

        { MKA8(bv, dB0, dB1) KROUND(bv, pB0, pB1) }
        pB0 = qB0; pB1 = qB1; qB0 = wf[128]; qB1 = wf[192];

        wq += 256;
        dA0 = eA0; dA1 = eA1; dB0 = eB0; dB1 = eB1;
        eA0 = fA0; eA1 = fA1; eB0 = fB0; eB1 = fB1;
    }
    // p* = tiles 20,21; qA* = tile 22; eA = drow[44],[45]
    {
        { MKA8(av, dA0, dA1) KROUND(av, pA0, pA1) }
        { MKA8(bv, dB0, dB1) KROUND(bv, pB0, pB1) }
        { MKA8(cv, eA0, eA1) KROUND(cv, qA0, qA1) }
    }
#undef KROUND
#undef MKA8
#undef PKD
#undef XZ

    // ---- dump raw partial to global, no barrier. C/D layout:
    //      col = lane&31 (+32 for B), row el = (rg&3) + 8*(rg>>2) + 4*lh ----
    float* pdst = partials + ((size_t)blockIdx.x * 4 + wave) * 2048;
#pragma unroll
    for (int rg = 0; rg < 16; ++rg) {
        const int el = (rg & 3) + 8 * (rg >> 2) + 4 * lh;
        pdst[el * 64 + m]      = accA[rg];
        pdst[el * 64 + 32 + m] = accB[rg];
    }
}

// ---------------------------------------------------------------------------
// Kernel 2 — tail: sum 4 partials + b1 + ssp -> h1 (LDS) -> layers 2/3 +
// asy + output. R17: W2 staged in LDS (16 KB); ds_read_b128 2-way = free.
// ---------------------------------------------------------------------------
__global__ __launch_bounds__(BLOCK)
void wfnet_tail(const float* __restrict__ rs,
                const float* __restrict__ coords,
                const float* __restrict__ charges,
                const float* __restrict__ partials,
                const float* __restrict__ b1,
                const float* __restrict__ W2,
                const float* __restrict__ b2,
                const float* __restrict__ W3,
                const float* __restrict__ b3,
                float* __restrict__ out)
{
    __shared__ float lds_rs[TB * N_EL * 3];   // 6 KB
    __shared__ float lds_h1[TB * H1LD];       // 8.7 KB
    __shared__ float lds_w2[HIDDEN * HIDDEN]; // 16 KB

    const int tid = threadIdx.x;
    const int el  = tid >> 3;                // 0..31
    const int g   = tid & 7;
    const int b   = blockIdx.x * TB + el;

    // stage rs for asy
    {
        const float* rs_blk = rs + (size_t)blockIdx.x * (TB * N_EL * 3);
        for (int k = tid; k < TB * N_EL * 3; k += BLOCK) lds_rs[k] = rs_blk[k];
    }
    // stage W2 (4 float4 per thread)
    {
        float4* dst = (float4*)lds_w2;
        const float4* src = (const float4*)W2;
#pragma unroll
        for (int i = 0; i < 4; ++i) dst[tid + 256 * i] = src[tid + 256 * i];
    }

    // sum 4 wave-partials for (el, cols g*8..g*8+7), + b1, ssp -> LDS h1
    {
        const float* pb = partials + (size_t)blockIdx.x * 8192 + el * 64 + g * 8;
        const float4 p00 = ((const float4*)(pb + 0 * 2048))[0];
        const float4 p01 = ((const float4*)(pb + 0 * 2048))[1];
        const float4 p10 = ((const float4*)(pb + 1 * 2048))[0];
        const float4 p11 = ((const float4*)(pb + 1 * 2048))[1];
        const float4 p20 = ((const float4*)(pb + 2 * 2048))[0];
        const float4 p21 = ((const float4*)(pb + 2 * 2048))[1];
        const float4 p30 = ((const float4*)(pb + 3 * 2048))[0];
        const float4 p31 = ((const float4*)(pb + 3 * 2048))[1];
        const float4 ba = ((const float4*)(b1 + g * 8))[0];
        const float4 bb = ((const float4*)(b1 + g * 8))[1];
        float* h1w = lds_h1 + el * H1LD + g * 8;
        h1w[0] = ssp(p00.x + p10.x + p20.x + p30.x + ba.x);
        h1w[1] = ssp(p00.y + p10.y + p20.y + p30.y + ba.y);
        h1w[2] = ssp(p00.z + p10.z + p20.z + p30.z + ba.z);
        h1w[3] = ssp(p00.w + p10.w + p20.w + p30.w + ba.w);
        h1w[4] = ssp(p01.x + p11.x + p21.x + p31.x + bb.x);
        h1w[5] = ssp(p01.y + p11.y + p21.y + p31.y + bb.y);
        h1w[6] = ssp(p01.z + p11.z + p21.z + p31.z + bb.z);
        h1w[7] = ssp(p01.w + p11.w + p21.w + p31.w + bb.w);
    }

    // asy partial: this thread's 8 el-nuc pairs (needs only lds_rs)
    float asy = 0.0f;
    __syncthreads();   // rs + W2 staged AND h1 visible
    {
        const float* myrs = lds_rs + el * (N_EL * 3);
        const float4 ch = *(const float4*)charges;
#pragma unroll
        for (int i = 0; i < 8; ++i) {
            const int p = g + 8 * i;
            const int e = p >> 2, n = p & 3;
            const float dx = myrs[e * 3 + 0] - coords[n * 3 + 0];
            const float dy = myrs[e * 3 + 1] - coords[n * 3 + 1];
            const float dz = myrs[e * 3 + 2] - coords[n * 3 + 2];
            const float d = sqrtf(dx * dx + dy * dy + dz * dz);
            const float Z = (n < 2) ? ((n == 0) ? ch.x : ch.y)
                                    : ((n == 2) ? ch.z : ch.w);
            asy += (Z * d + d * d) / (1.0f + d);   // decay = sqrt(2*0.5) = 1
        }
    }
    asy = redg(asy);

    // layers 2/3 (W2 from LDS)
    const float4* __restrict__ W2v = (const float4*)lds_w2;
    const float4* __restrict__ b2v = (const float4*)b2;
    const int wbi = g * 2;
    const float4 b2a = b2v[wbi], b2b = b2v[wbi + 1];
    float s0 = b2a.x, s1 = b2a.y, s2 = b2a.z, s3 = b2a.w;
    float s4 = b2b.x, s5 = b2b.y, s6 = b2b.z, s7 = b2b.w;

    const float* __restrict__ h1row = lds_h1 + el * H1LD;
    for (int k = 0; k < HIDDEN; ++k) {
        const float hk  = h1row[k];
        const float4 wa = W2v[k * 16 + wbi];
        const float4 wb = W2v[k * 16 + wbi + 1];
        s0 = fmaf(hk, wa.x, s0); s1 = fmaf(hk, wa.y, s1);
        s2 = fmaf(hk, wa.z, s2); s3 = fmaf(hk, wa.w, s3);
        s4 = fmaf(hk, wb.x, s4); s5 = fmaf(hk, wb.y, s5);
        s6 = fmaf(hk, wb.z, s6); s7 = fmaf(hk, wb.w, s7);
    }

    const float4* __restrict__ W3v = (const float4*)W3;
    const float4 w3a = W3v[wbi], w3b = W3v[wbi + 1];
    float part = ssp(s0) * w3a.x + ssp(s1) * w3a.y
               + ssp(s2) * w3a.z + ssp(s3) * w3a.w
               + ssp(s4) * w3b.x + ssp(s5) * w3b.y
               + ssp(s6) * w3b.z + ssp(s7) * w3b.w;
    part = redg(part);

    if (g == 0) {
        const float ys = part + b3[0];
        out[b] = __expf(ys) * __expf(-asy);
    }
}

extern "C" void kernel_launch(void* const* d_in, const int* in_sizes, int n_in,
                              void* d_out, int out_size, void* d_ws, size_t ws_size,
                              hipStream_t stream) {
    const float* rs      = (const float*)d_in[0];
    const float* coords  = (const float*)d_in[1];
    const float* charges = (const float*)d_in[2];
    const float* W1      = (const float*)d_in[3];
    const float* b1      = (const float*)d_in[4];
    const float* W2      = (const float*)d_in[5];
    const float* b2      = (const float*)d_in[6];
    const float* W3      = (const float*)d_in[7];
    const float* b3      = (const float*)d_in[8];
    float* out = (float*)d_out;

    const int batch = in_sizes[0] / (N_EL * 3);   // 32768
    intx8* w1f8     = (intx8*)d_ws;               // 368 KB fp8 W1
    float* partials = (float*)((char*)d_ws + WS_PART_OFF);  // 32 MB

    prep_w1_kernel<<<N_PAIRS / 2, 256, 0, stream>>>(W1, w1f8);
    wfnet_gemm<<<batch / TB, BLOCK, 0, stream>>>(rs, coords, w1f8, partials);
    wfnet_tail<<<batch / TB, BLOCK, 0, stream>>>(rs, coords, charges, partials,
                                                 b1, W2, b2, W3, b3, out);
}

// Round 8
// 137.680 us; speedup vs baseline: 1.1020x; 1.0514x over previous
//
#include <hip/hip_runtime.h>
#include <math.h>

#define N_EL    16
#define N_NUC   4
#define N_FEATS 32
#define N_PAIRS 184
#define HIDDEN  64
#define TB      32           // batch elements per block
#define BLOCK   256
#define DLD     185          // dist LDS stride
#define H1LD    68           // h1 stride in kernel 2
#define TPW     23           // K-tiles (2 pairs each) per wave; 4*23*2 = 184
#define WS_PART_OFF (1 << 19)   // partials start at 512 KB into d_ws

typedef int   intx8    __attribute__((ext_vector_type(8)));
typedef float floatx16 __attribute__((ext_vector_type(16)));

// triu_indices(16, 1)
__constant__ unsigned char c_I[120] = {
    0,0,0,0,0,0,0,0,0,0,0,0,0,0,0,
    1,1,1,1,1,1,1,1,1,1,1,1,1,1,
    2,2,2,2,2,2,2,2,2,2,2,2,2,
    3,3,3,3,3,3,3,3,3,3,3,3,
    4,4,4,4,4,4,4,4,4,4,4,
    5,5,5,5,5,5,5,5,5,5,
    6,6,6,6,6,6,6,6,6,
    7,7,7,7,7,7,7,7,
    8,8,8,8,8,8,8,
    9,9,9,9,9,9,
    10,10,10,10,10,
    11,11,11,11,
    12,12,12,
    13,13,
    14
};
__constant__ unsigned char c_J[120] = {
    1,2,3,4,5,6,7,8,9,10,11,12,13,14,15,
    2,3,4,5,6,7,8,9,10,11,12,13,14,15,
    3,4,5,6,7,8,9,10,11,12,13,14,15,
    4,5,6,7,8,9,10,11,12,13,14,15,
    5,6,7,8,9,10,11,12,13,14,15,
    6,7,8,9,10,11,12,13,14,15,
    7,8,9,10,11,12,13,14,15,
    8,9,10,11,12,13,14,15,
    9,10,11,12,13,14,15,
    10,11,12,13,14,15,
    11,12,13,14,15,
    12,13,14,15,
    13,14,15,
    14,15,
    15
};

__device__ __forceinline__ float ssp(float x) {
    float a = fabsf(x);
    return fmaxf(x, 0.0f) + log1pf(__expf(-a)) - 0.69314718056f;
}
__device__ __forceinline__ float redg(float v) {
    v += __shfl_xor(v, 1);
    v += __shfl_xor(v, 2);
    v += __shfl_xor(v, 4);
    return v;
}

// ---------------------------------------------------------------------------
// Prep (verified R14): W1 -> fp8 e4m3 (pre-scaled 2^6; MFMA applies 2^-6 via
// scale_b) in 32x32x64 B-fragment order.
// ---------------------------------------------------------------------------
__global__ __launch_bounds__(256)
void prep_w1_kernel(const float* __restrict__ W1, intx8* __restrict__ ws)
{
    __shared__ float w[2 * N_FEATS * HIDDEN];   // 16 KB: two pairs' rows
    const int t = blockIdx.x;
    const float* src = W1 + (size_t)(2 * t) * (N_FEATS * HIDDEN);
    for (int k = threadIdx.x; k < 2 * N_FEATS * HIDDEN; k += 256) w[k] = src[k];
    __syncthreads();

    const int tid = threadIdx.x;
    if (tid >= 128) return;
    const int lane = tid & 63;
    const int nh   = tid >> 6;
    const int lh   = lane >> 5;
    const int col  = nh * 32 + (lane & 31);
    const int fb   = lh * 16;
    intx8 frag;
#pragma unroll
    for (int r = 0; r < 8; ++r) {
        const int pair = r >> 2;
        const int fo   = fb + ((r & 3) << 2);
        const float v0 = 64.0f * w[(pair * N_FEATS + fo + 0) * 64 + col];
        const float v1 = 64.0f * w[(pair * N_FEATS + fo + 1) * 64 + col];
        const float v2 = 64.0f * w[(pair * N_FEATS + fo + 2) * 64 + col];
        const float v3 = 64.0f * w[(pair * N_FEATS + fo + 3) * 64 + col];
        int d = __builtin_amdgcn_cvt_pk_fp8_f32(v0, v1, 0, false);
        d     = __builtin_amdgcn_cvt_pk_fp8_f32(v2, v3, d, true);
        frag[r] = d;
    }
    ws[(size_t)(t * 2 + nh) * 64 + lane] = frag;
}

// ---------------------------------------------------------------------------
// Kernel 1 — GEMM (R19 structure, verified absmax 0).
// R23: 2-deep wq pipeline, NO min-waves launch bound. R22's (256,4) bound
// capped VGPR at 64 and spilled the pipeline regs (FETCH 34 MB / WRITE 77 MB
// scratch traffic). Little's law says depth-1 = 256 B in flight / 200 cy L2
// latency = 1.28 B/cy/wave — exactly the measured K-loop throughput; depth-2
// doubles in-flight bytes. Expected ~100-110 VGPR, still 4 waves/SIMD.
// it>=8 prefetch over-reads <=12 KB past the 368 KB W1 image into the ws pad
// below WS_PART_OFF (allocated, values unused).
// ---------------------------------------------------------------------------
__global__ __launch_bounds__(BLOCK)
void wfnet_gemm(const float* __restrict__ rs,
                const float* __restrict__ coords,
                const intx8* __restrict__ ws,
                float* __restrict__ partials)
{
    __shared__ float lds_rs[TB * N_EL * 3];   // 6 KB
    __shared__ float lds_dist[TB * DLD];      // 23.7 KB

    const int tid  = threadIdx.x;
    const int wave = tid >> 6;               // = kh
    const int lane = tid & 63;
    const int m    = lane & 31;
    const int lh   = lane >> 5;

    // ---- phase 1: stage rs ----
    {
        const float* rs_blk = rs + (size_t)blockIdx.x * (TB * N_EL * 3);
        for (int k = tid; k < TB * N_EL * 3; k += BLOCK) lds_rs[k] = rs_blk[k];
    }
    __syncthreads();

    // ---- phase 2: distances only ----
    {
        const int bl = tid >> 3, g = tid & 7;
        const float* myrs = lds_rs + bl * (N_EL * 3);
        float* dst = lds_dist + bl * DLD;
        for (int i = 0; i < 8; ++i) {
            const int p = g + 8 * i;
            const int e = p >> 2, n = p & 3;
            const float dx = myrs[e * 3 + 0] - coords[n * 3 + 0];
            const float dy = myrs[e * 3 + 1] - coords[n * 3 + 1];
            const float dz = myrs[e * 3 + 2] - coords[n * 3 + 2];
            dst[p] = sqrtf(dx * dx + dy * dy + dz * dz);
        }
        for (int i = 0; i < 15; ++i) {
            const int q  = g + 8 * i;
            const int ei = 3 * (int)c_I[q], ej = 3 * (int)c_J[q];
            const float dx = myrs[ei + 0] - myrs[ej + 0];
            const float dy = myrs[ei + 1] - myrs[ej + 1];
            const float dz = myrs[ei + 2] - myrs[ej + 2];
            dst[64 + q] = sqrtf(dx * dx + dy * dy + dz * dz);
        }
    }
    __syncthreads();

    // per-lane Gaussian constants for feats lh*16 .. lh*16+15
    // P1 = sqrt(8*log2 e)/sigma; byte = sat_u8(56.5 - (d*P1+P0)^2)
    const int f0 = lh * 16;
#define MKC(P, FF) float P##1, P##0; { \
    const float fq = (float)(FF) * (1.0f / 31.0f); \
    const float mu = 10.0f * fq * fq; \
    const float is = 7.0f / (1.0f + 10.0f * fq); \
    P##1 = is * 3.3972871404442143f; \
    P##0 = -mu * P##1; }
    MKC(F0_,  f0 + 0)  MKC(F1_,  f0 + 1)  MKC(F2_,  f0 + 2)  MKC(F3_,  f0 + 3)
    MKC(F4_,  f0 + 4)  MKC(F5_,  f0 + 5)  MKC(F6_,  f0 + 6)  MKC(F7_,  f0 + 7)
    MKC(F8_,  f0 + 8)  MKC(F9_,  f0 + 9)  MKC(F10_, f0 + 10) MKC(F11_, f0 + 11)
    MKC(F12_, f0 + 12) MKC(F13_, f0 + 13) MKC(F14_, f0 + 14) MKC(F15_, f0 + 15)
#undef MKC

    floatx16 accA = {};
    floatx16 accB = {};
    const intx8* wq = ws + ((size_t)(wave * TPW) * 128 + lane);
    const float* drow = lds_dist + m * DLD + wave * (2 * TPW);

    // z = 56.5 - t^2 (>=0 only near the Gaussian center; cvt clamps the rest)
#define XZ(dd, P) ({ const float t_ = fmaf(dd, P##1, P##0); fmaf(t_, -t_, 56.5f); })
#define PKD(dd, A, B, C, D) ({ \
    unsigned w_; \
    w_ = __builtin_amdgcn_cvt_pk_u8_f32(XZ(dd, A), 0, 0u); \
    w_ = __builtin_amdgcn_cvt_pk_u8_f32(XZ(dd, B), 1, w_); \
    w_ = __builtin_amdgcn_cvt_pk_u8_f32(XZ(dd, C), 2, w_); \
    w_ = __builtin_amdgcn_cvt_pk_u8_f32(XZ(dd, D), 3, w_); \
    (int)w_; })
#define MKA8(AV, dx0, dx1) \
    intx8 AV; { \
    AV[0] = PKD(dx0, F0_,  F1_,  F2_,  F3_);  \
    AV[1] = PKD(dx0, F4_,  F5_,  F6_,  F7_);  \
    AV[2] = PKD(dx0, F8_,  F9_,  F10_, F11_); \
    AV[3] = PKD(dx0, F12_, F13_, F14_, F15_); \
    AV[4] = PKD(dx1, F0_,  F1_,  F2_,  F3_);  \
    AV[5] = PKD(dx1, F4_,  F5_,  F6_,  F7_);  \
    AV[6] = PKD(dx1, F8_,  F9_,  F10_, F11_); \
    AV[7] = PKD(dx1, F12_, F13_, F14_, F15_); }
#define KROUND(AV, Q0, Q1) { \
    accA = __builtin_amdgcn_mfma_scale_f32_32x32x64_f8f6f4( \
               AV, Q0, accA, 0, 0, 0, 0x7F7F7F7F, 0, 0x79797979); \
    accB = __builtin_amdgcn_mfma_scale_f32_32x32x64_f8f6f4( \
               AV, Q1, accB, 0, 0, 0, 0x7F7F7F7F, 0, 0x79797979); }

    // 2-deep pipeline: p* = tiles (2it, 2it+1); q* = tiles (2it+2, 2it+3)
    intx8 pA0 = wq[0],   pA1 = wq[64];
    intx8 pB0 = wq[128], pB1 = wq[192];
    intx8 qA0 = wq[256], qA1 = wq[320];
    intx8 qB0 = wq[384], qB1 = wq[448];
    float dA0 = drow[0], dA1 = drow[1];
    float dB0 = drow[2], dB1 = drow[3];
    float eA0 = drow[4], eA1 = drow[5];
    float eB0 = drow[6], eB1 = drow[7];

    for (int it = 0; it < 10; ++it) {
        const intx8* wf = wq + 512;                        // tiles 2it+4,2it+5
        const int dfA = 4 * it + 8;                        // <=44: in-bounds
        const int dfB = (it < 9) ? (4 * it + 10) : 40;     // clamp (unused @9)
        const float fA0 = drow[dfA],     fA1 = drow[dfA + 1];
        const float fB0 = drow[dfB],     fB1 = drow[dfB + 1];

        { MKA8(av, dA0, dA1) KROUND(av, pA0, pA1) }
        pA0 = qA0; pA1 = qA1; qA0 = wf[0]; qA1 = wf[64];

        { MKA8(bv, dB0, dB1) KROUND(bv, pB0, pB1) }
        pB0 = qB0; pB1 = qB1; qB0 = wf[128]; qB1 = wf[192];

        wq += 256;
        dA0 = eA0; dA1 = eA1; dB0 = eB0; dB1 = eB1;
        eA0 = fA0; eA1 = fA1; eB0 = fB0; eB1 = fB1;
    }
    // p* = tiles 20,21; qA* = tile 22; eA = drow[44],[45]
    {
        { MKA8(av, dA0, dA1) KROUND(av, pA0, pA1) }
        { MKA8(bv, dB0, dB1) KROUND(bv, pB0, pB1) }
        { MKA8(cv, eA0, eA1) KROUND(cv, qA0, qA1) }
    }
#undef KROUND
#undef MKA8
#undef PKD
#undef XZ

    // ---- dump raw partial to global, no barrier. C/D layout:
    //      col = lane&31 (+32 for B), row el = (rg&3) + 8*(rg>>2) + 4*lh ----
    float* pdst = partials + ((size_t)blockIdx.x * 4 + wave) * 2048;
#pragma unroll
    for (int rg = 0; rg < 16; ++rg) {
        const int el = (rg & 3) + 8 * (rg >> 2) + 4 * lh;
        pdst[el * 64 + m]      = accA[rg];
        pdst[el * 64 + 32 + m] = accB[rg];
    }
}

// ---------------------------------------------------------------------------
// Kernel 2 — tail: sum 4 partials + b1 + ssp -> h1 (LDS) -> layers 2/3 +
// asy + output. R17: W2 staged in LDS (16 KB); ds_read_b128 2-way = free.
// ---------------------------------------------------------------------------
__global__ __launch_bounds__(BLOCK)
void wfnet_tail(const float* __restrict__ rs,
                const float* __restrict__ coords,
                const float* __restrict__ charges,
                const float* __restrict__ partials,
                const float* __restrict__ b1,
                const float* __restrict__ W2,
                const float* __restrict__ b2,
                const float* __restrict__ W3,
                const float* __restrict__ b3,
                float* __restrict__ out)
{
    __shared__ float lds_rs[TB * N_EL * 3];   // 6 KB
    __shared__ float lds_h1[TB * H1LD];       // 8.7 KB
    __shared__ float lds_w2[HIDDEN * HIDDEN]; // 16 KB

    const int tid = threadIdx.x;
    const int el  = tid >> 3;                // 0..31
    const int g   = tid & 7;
    const int b   = blockIdx.x * TB + el;

    // stage rs for asy
    {
        const float* rs_blk = rs + (size_t)blockIdx.x * (TB * N_EL * 3);
        for (int k = tid; k < TB * N_EL * 3; k += BLOCK) lds_rs[k] = rs_blk[k];
    }
    // stage W2 (4 float4 per thread)
    {
        float4* dst = (float4*)lds_w2;
        const float4* src = (const float4*)W2;
#pragma unroll
        for (int i = 0; i < 4; ++i) dst[tid + 256 * i] = src[tid + 256 * i];
    }

    // sum 4 wave-partials for (el, cols g*8..g*8+7), + b1, ssp -> LDS h1
    {
        const float* pb = partials + (size_t)blockIdx.x * 8192 + el * 64 + g * 8;
        const float4 p00 = ((const float4*)(pb + 0 * 2048))[0];
        const float4 p01 = ((const float4*)(pb + 0 * 2048))[1];
        const float4 p10 = ((const float4*)(pb + 1 * 2048))[0];
        const float4 p11 = ((const float4*)(pb + 1 * 2048))[1];
        const float4 p20 = ((const float4*)(pb + 2 * 2048))[0];
        const float4 p21 = ((const float4*)(pb + 2 * 2048))[1];
        const float4 p30 = ((const float4*)(pb + 3 * 2048))[0];
        const float4 p31 = ((const float4*)(pb + 3 * 2048))[1];
        const float4 ba = ((const float4*)(b1 + g * 8))[0];
        const float4 bb = ((const float4*)(b1 + g * 8))[1];
        float* h1w = lds_h1 + el * H1LD + g * 8;
        h1w[0] = ssp(p00.x + p10.x + p20.x + p30.x + ba.x);
        h1w[1] = ssp(p00.y + p10.y + p20.y + p30.y + ba.y);
        h1w[2] = ssp(p00.z + p10.z + p20.z + p30.z + ba.z);
        h1w[3] = ssp(p00.w + p10.w + p20.w + p30.w + ba.w);
        h1w[4] = ssp(p01.x + p11.x + p21.x + p31.x + bb.x);
        h1w[5] = ssp(p01.y + p11.y + p21.y + p31.y + bb.y);
        h1w[6] = ssp(p01.z + p11.z + p21.z + p31.z + bb.z);
        h1w[7] = ssp(p01.w + p11.w + p21.w + p31.w + bb.w);
    }

    // asy partial: this thread's 8 el-nuc pairs (needs only lds_rs)
    float asy = 0.0f;
    __syncthreads();   // rs + W2 staged AND h1 visible
    {
        const float* myrs = lds_rs + el * (N_EL * 3);
        const float4 ch = *(const float4*)charges;
#pragma unroll
        for (int i = 0; i < 8; ++i) {
            const int p = g + 8 * i;
            const int e = p >> 2, n = p & 3;
            const float dx = myrs[e * 3 + 0] - coords[n * 3 + 0];
            const float dy = myrs[e * 3 + 1] - coords[n * 3 + 1];
            const float dz = myrs[e * 3 + 2] - coords[n * 3 + 2];
            const float d = sqrtf(dx * dx + dy * dy + dz * dz);
            const float Z = (n < 2) ? ((n == 0) ? ch.x : ch.y)
                                    : ((n == 2) ? ch.z : ch.w);
            asy += (Z * d + d * d) / (1.0f + d);   // decay = sqrt(2*0.5) = 1
        }
    }
    asy = redg(asy);

    // layers 2/3 (W2 from LDS)
    const float4* __restrict__ W2v = (const float4*)lds_w2;
    const float4* __restrict__ b2v = (const float4*)b2;
    const int wbi = g * 2;
    const float4 b2a = b2v[wbi], b2b = b2v[wbi + 1];
    float s0 = b2a.x, s1 = b2a.y, s2 = b2a.z, s3 = b2a.w;
    float s4 = b2b.x, s5 = b2b.y, s6 = b2b.z, s7 = b2b.w;

    const float* __restrict__ h1row = lds_h1 + el * H1LD;
    for (int k = 0; k < HIDDEN; ++k) {
        const float hk  = h1row[k];
        const float4 wa = W2v[k * 16 + wbi];
        const float4 wb = W2v[k * 16 + wbi + 1];
        s0 = fmaf(hk, wa.x, s0); s1 = fmaf(hk, wa.y, s1);
        s2 = fmaf(hk, wa.z, s2); s3 = fmaf(hk, wa.w, s3);
        s4 = fmaf(hk, wb.x, s4); s5 = fmaf(hk, wb.y, s5);
        s6 = fmaf(hk, wb.z, s6); s7 = fmaf(hk, wb.w, s7);
    }

    const float4* __restrict__ W3v = (const float4*)W3;
    const float4 w3a = W3v[wbi], w3b = W3v[wbi + 1];
    float part = ssp(s0) * w3a.x + ssp(s1) * w3a.y
               + ssp(s2) * w3a.z + ssp(s3) * w3a.w
               + ssp(s4) * w3b.x + ssp(s5) * w3b.y
               + ssp(s6) * w3b.z + ssp(s7) * w3b.w;
    part = redg(part);

    if (g == 0) {
        const float ys = part + b3[0];
        out[b] = __expf(ys) * __expf(-asy);
    }
}

extern "C" void kernel_launch(void* const* d_in, const int* in_sizes, int n_in,
                              void* d_out, int out_size, void* d_ws, size_t ws_size,
                              hipStream_t stream) {
    const float* rs      = (const float*)d_in[0];
    const float* coords  = (const float*)d_in[1];
    const float* charges = (const float*)d_in[2];
    const float* W1      = (const float*)d_in[3];
    const float* b1      = (const float*)d_in[4];
    const float* W2      = (const float*)d_in[5];
    const float* b2      = (const float*)d_in[6];
    const float* W3      = (const float*)d_in[7];
    const float* b3      = (const float*)d_in[8];
    float* out = (float*)d_out;

    const int batch = in_sizes[0] / (N_EL * 3);   // 32768
    intx8* w1f8     = (intx8*)d_ws;               // 368 KB fp8 W1
    float* partials = (float*)((char*)d_ws + WS_PART_OFF);  // 32 MB

    prep_w1_kernel<<<N_PAIRS / 2, 256, 0, stream>>>(W1, w1f8);
    wfnet_gemm<<<batch / TB, BLOCK, 0, stream>>>(rs, coords, w1f8, partials);
    wfnet_tail<<<batch / TB, BLOCK, 0, stream>>>(rs, coords, charges, partials,
                                                 b1, W2, b2, W3, b3, out);
}

// Round 9
// 129.942 us; speedup vs baseline: 1.1676x; 1.0596x over previous
//
#include <hip/hip_runtime.h>
#include <math.h>

#define N_EL    16
#define N_NUC   4
#define N_FEATS 32
#define N_PAIRS 184
#define HIDDEN  64
#define TB      32           // batch elements per block
#define BLOCK   256
#define DLD     185          // dist LDS stride
#define H1LD    68           // h1 stride in kernel 2
#define TPW     23           // K-tiles (2 pairs each) per wave; 4*23*2 = 184
#define WS_PART_OFF (1 << 19)   // partials start at 512 KB into d_ws

typedef int   intx8    __attribute__((ext_vector_type(8)));
typedef float floatx16 __attribute__((ext_vector_type(16)));

// triu_indices(16, 1)
__constant__ unsigned char c_I[120] = {
    0,0,0,0,0,0,0,0,0,0,0,0,0,0,0,
    1,1,1,1,1,1,1,1,1,1,1,1,1,1,
    2,2,2,2,2,2,2,2,2,2,2,2,2,
    3,3,3,3,3,3,3,3,3,3,3,3,
    4,4,4,4,4,4,4,4,4,4,4,
    5,5,5,5,5,5,5,5,5,5,
    6,6,6,6,6,6,6,6,6,
    7,7,7,7,7,7,7,7,
    8,8,8,8,8,8,8,
    9,9,9,9,9,9,
    10,10,10,10,10,
    11,11,11,11,
    12,12,12,
    13,13,
    14
};
__constant__ unsigned char c_J[120] = {
    1,2,3,4,5,6,7,8,9,10,11,12,13,14,15,
    2,3,4,5,6,7,8,9,10,11,12,13,14,15,
    3,4,5,6,7,8,9,10,11,12,13,14,15,
    4,5,6,7,8,9,10,11,12,13,14,15,
    5,6,7,8,9,10,11,12,13,14,15,
    6,7,8,9,10,11,12,13,14,15,
    7,8,9,10,11,12,13,14,15,
    8,9,10,11,12,13,14,15,
    9,10,11,12,13,14,15,
    10,11,12,13,14,15,
    11,12,13,14,15,
    12,13,14,15,
    13,14,15,
    14,15,
    15
};

__device__ __forceinline__ float ssp(float x) {
    float a = fabsf(x);
    return fmaxf(x, 0.0f) + log1pf(__expf(-a)) - 0.69314718056f;
}
__device__ __forceinline__ float redg(float v) {
    v += __shfl_xor(v, 1);
    v += __shfl_xor(v, 2);
    v += __shfl_xor(v, 4);
    return v;
}

// ---------------------------------------------------------------------------
// Prep (verified R14): W1 -> fp8 e4m3 (pre-scaled 2^6; MFMA applies 2^-6 via
// scale_b) in 32x32x64 B-fragment order.
// ---------------------------------------------------------------------------
__global__ __launch_bounds__(256)
void prep_w1_kernel(const float* __restrict__ W1, intx8* __restrict__ ws)
{
    __shared__ float w[2 * N_FEATS * HIDDEN];   // 16 KB: two pairs' rows
    const int t = blockIdx.x;
    const float* src = W1 + (size_t)(2 * t) * (N_FEATS * HIDDEN);
    for (int k = threadIdx.x; k < 2 * N_FEATS * HIDDEN; k += 256) w[k] = src[k];
    __syncthreads();

    const int tid = threadIdx.x;
    if (tid >= 128) return;
    const int lane = tid & 63;
    const int nh   = tid >> 6;
    const int lh   = lane >> 5;
    const int col  = nh * 32 + (lane & 31);
    const int fb   = lh * 16;
    intx8 frag;
#pragma unroll
    for (int r = 0; r < 8; ++r) {
        const int pair = r >> 2;
        const int fo   = fb + ((r & 3) << 2);
        const float v0 = 64.0f * w[(pair * N_FEATS + fo + 0) * 64 + col];
        const float v1 = 64.0f * w[(pair * N_FEATS + fo + 1) * 64 + col];
        const float v2 = 64.0f * w[(pair * N_FEATS + fo + 2) * 64 + col];
        const float v3 = 64.0f * w[(pair * N_FEATS + fo + 3) * 64 + col];
        int d = __builtin_amdgcn_cvt_pk_fp8_f32(v0, v1, 0, false);
        d     = __builtin_amdgcn_cvt_pk_fp8_f32(v2, v3, d, true);
        frag[r] = d;
    }
    ws[(size_t)(t * 2 + nh) * 64 + lane] = frag;
}

// ---------------------------------------------------------------------------
// Kernel 1 — GEMM (R19 data path, verified absmax 0).
// R24: #pragma unroll 1 on the K-loop. Theory: wall pinned at 44-50 us across
// 5 rounds of data-path changes (VALU halved twice, load depth doubled) with
// ~40% of cycles un-issuable and all data pipes <50% -> instruction-fetch
// bound. Fully-unrolled K-loop is ~2300 inst (~20 KB), marginal vs the 32 KB
// L1 I-cache; rolled body ~1.8 KB is I$-resident. R19's in-iteration wq/drow
// prefetch (rotation registers) is preserved.
// ---------------------------------------------------------------------------
__global__ __launch_bounds__(BLOCK)
void wfnet_gemm(const float* __restrict__ rs,
                const float* __restrict__ coords,
                const intx8* __restrict__ ws,
                float* __restrict__ partials)
{
    __shared__ float lds_rs[TB * N_EL * 3];   // 6 KB
    __shared__ float lds_dist[TB * DLD];      // 23.7 KB

    const int tid  = threadIdx.x;
    const int wave = tid >> 6;               // = kh
    const int lane = tid & 63;
    const int m    = lane & 31;
    const int lh   = lane >> 5;

    // ---- phase 1: stage rs ----
    {
        const float* rs_blk = rs + (size_t)blockIdx.x * (TB * N_EL * 3);
        for (int k = tid; k < TB * N_EL * 3; k += BLOCK) lds_rs[k] = rs_blk[k];
    }
    __syncthreads();

    // ---- phase 2: distances only ----
    {
        const int bl = tid >> 3, g = tid & 7;
        const float* myrs = lds_rs + bl * (N_EL * 3);
        float* dst = lds_dist + bl * DLD;
        for (int i = 0; i < 8; ++i) {
            const int p = g + 8 * i;
            const int e = p >> 2, n = p & 3;
            const float dx = myrs[e * 3 + 0] - coords[n * 3 + 0];
            const float dy = myrs[e * 3 + 1] - coords[n * 3 + 1];
            const float dz = myrs[e * 3 + 2] - coords[n * 3 + 2];
            dst[p] = sqrtf(dx * dx + dy * dy + dz * dz);
        }
        for (int i = 0; i < 15; ++i) {
            const int q  = g + 8 * i;
            const int ei = 3 * (int)c_I[q], ej = 3 * (int)c_J[q];
            const float dx = myrs[ei + 0] - myrs[ej + 0];
            const float dy = myrs[ei + 1] - myrs[ej + 1];
            const float dz = myrs[ei + 2] - myrs[ej + 2];
            dst[64 + q] = sqrtf(dx * dx + dy * dy + dz * dz);
        }
    }
    __syncthreads();

    // per-lane Gaussian constants for feats lh*16 .. lh*16+15
    // P1 = sqrt(8*log2 e)/sigma; byte = sat_u8(56.5 - (d*P1+P0)^2)
    const int f0 = lh * 16;
#define MKC(P, FF) float P##1, P##0; { \
    const float fq = (float)(FF) * (1.0f / 31.0f); \
    const float mu = 10.0f * fq * fq; \
    const float is = 7.0f / (1.0f + 10.0f * fq); \
    P##1 = is * 3.3972871404442143f; \
    P##0 = -mu * P##1; }
    MKC(F0_,  f0 + 0)  MKC(F1_,  f0 + 1)  MKC(F2_,  f0 + 2)  MKC(F3_,  f0 + 3)
    MKC(F4_,  f0 + 4)  MKC(F5_,  f0 + 5)  MKC(F6_,  f0 + 6)  MKC(F7_,  f0 + 7)
    MKC(F8_,  f0 + 8)  MKC(F9_,  f0 + 9)  MKC(F10_, f0 + 10) MKC(F11_, f0 + 11)
    MKC(F12_, f0 + 12) MKC(F13_, f0 + 13) MKC(F14_, f0 + 14) MKC(F15_, f0 + 15)
#undef MKC

    floatx16 accA = {};
    floatx16 accB = {};
    const intx8* wq = ws + ((size_t)(wave * TPW) * 128 + lane);
    const float* drow = lds_dist + m * DLD + wave * (2 * TPW);

    // z = 56.5 - t^2 (>=0 only near the Gaussian center; cvt clamps the rest)
#define XZ(dd, P) ({ const float t_ = fmaf(dd, P##1, P##0); fmaf(t_, -t_, 56.5f); })
#define PKD(dd, A, B, C, D) ({ \
    unsigned w_; \
    w_ = __builtin_amdgcn_cvt_pk_u8_f32(XZ(dd, A), 0, 0u); \
    w_ = __builtin_amdgcn_cvt_pk_u8_f32(XZ(dd, B), 1, w_); \
    w_ = __builtin_amdgcn_cvt_pk_u8_f32(XZ(dd, C), 2, w_); \
    w_ = __builtin_amdgcn_cvt_pk_u8_f32(XZ(dd, D), 3, w_); \
    (int)w_; })
#define MKA8(AV, dx0, dx1) \
    intx8 AV; { \
    AV[0] = PKD(dx0, F0_,  F1_,  F2_,  F3_);  \
    AV[1] = PKD(dx0, F4_,  F5_,  F6_,  F7_);  \
    AV[2] = PKD(dx0, F8_,  F9_,  F10_, F11_); \
    AV[3] = PKD(dx0, F12_, F13_, F14_, F15_); \
    AV[4] = PKD(dx1, F0_,  F1_,  F2_,  F3_);  \
    AV[5] = PKD(dx1, F4_,  F5_,  F6_,  F7_);  \
    AV[6] = PKD(dx1, F8_,  F9_,  F10_, F11_); \
    AV[7] = PKD(dx1, F12_, F13_, F14_, F15_); }
#define KROUND(AV, Q0, Q1) { \
    accA = __builtin_amdgcn_mfma_scale_f32_32x32x64_f8f6f4( \
               AV, Q0, accA, 0, 0, 0, 0x7F7F7F7F, 0, 0x79797979); \
    accB = __builtin_amdgcn_mfma_scale_f32_32x32x64_f8f6f4( \
               AV, Q1, accB, 0, 0, 0, 0x7F7F7F7F, 0, 0x79797979); }

    intx8 pA0 = wq[0],   pA1 = wq[64];
    intx8 pB0 = wq[128], pB1 = wq[192];
    float dA0 = drow[0], dA1 = drow[1];
    float dB0 = drow[2], dB1 = drow[3];

#pragma unroll 1
    for (int it = 0; it < 10; ++it) {
        const intx8* wn = wq + 256;
        const float eA0 = drow[4 * it + 4], eA1 = drow[4 * it + 5];
        const float eB0 = drow[4 * it + 6], eB1 = drow[4 * it + 7];

        { MKA8(av, dA0, dA1) KROUND(av, pA0, pA1) }
        pA0 = wn[0]; pA1 = wn[64];

        { MKA8(bv, dB0, dB1) KROUND(bv, pB0, pB1) }
        pB0 = wn[128]; pB1 = wn[192];

        wq = wn;
        dA0 = eA0; dA1 = eA1; dB0 = eB0; dB1 = eB1;
    }
    {
        const intx8* wn = wq + 256;
        const float eA0 = drow[44], eA1 = drow[45];
        { MKA8(av, dA0, dA1) KROUND(av, pA0, pA1) }
        pA0 = wn[0]; pA1 = wn[64];
        { MKA8(bv, dB0, dB1) KROUND(bv, pB0, pB1) }
        { MKA8(cv, eA0, eA1) KROUND(cv, pA0, pA1) }
    }
#undef KROUND
#undef MKA8
#undef PKD
#undef XZ

    // ---- dump raw partial to global, no barrier. C/D layout:
    //      col = lane&31 (+32 for B), row el = (rg&3) + 8*(rg>>2) + 4*lh ----
    float* pdst = partials + ((size_t)blockIdx.x * 4 + wave) * 2048;
#pragma unroll
    for (int rg = 0; rg < 16; ++rg) {
        const int el = (rg & 3) + 8 * (rg >> 2) + 4 * lh;
        pdst[el * 64 + m]      = accA[rg];
        pdst[el * 64 + 32 + m] = accB[rg];
    }
}

// ---------------------------------------------------------------------------
// Kernel 2 — tail: sum 4 partials + b1 + ssp -> h1 (LDS) -> layers 2/3 +
// asy + output. R17: W2 staged in LDS (16 KB); ds_read_b128 2-way = free.
// ---------------------------------------------------------------------------
__global__ __launch_bounds__(BLOCK)
void wfnet_tail(const float* __restrict__ rs,
                const float* __restrict__ coords,
                const float* __restrict__ charges,
                const float* __restrict__ partials,
                const float* __restrict__ b1,
                const float* __restrict__ W2,
                const float* __restrict__ b2,
                const float* __restrict__ W3,
                const float* __restrict__ b3,
                float* __restrict__ out)
{
    __shared__ float lds_rs[TB * N_EL * 3];   // 6 KB
    __shared__ float lds_h1[TB * H1LD];       // 8.7 KB
    __shared__ float lds_w2[HIDDEN * HIDDEN]; // 16 KB

    const int tid = threadIdx.x;
    const int el  = tid >> 3;                // 0..31
    const int g   = tid & 7;
    const int b   = blockIdx.x * TB + el;

    // stage rs for asy
    {
        const float* rs_blk = rs + (size_t)blockIdx.x * (TB * N_EL * 3);
        for (int k = tid; k < TB * N_EL * 3; k += BLOCK) lds_rs[k] = rs_blk[k];
    }
    // stage W2 (4 float4 per thread)
    {
        float4* dst = (float4*)lds_w2;
        const float4* src = (const float4*)W2;
#pragma unroll
        for (int i = 0; i < 4; ++i) dst[tid + 256 * i] = src[tid + 256 * i];
    }

    // sum 4 wave-partials for (el, cols g*8..g*8+7), + b1, ssp -> LDS h1
    {
        const float* pb = partials + (size_t)blockIdx.x * 8192 + el * 64 + g * 8;
        const float4 p00 = ((const float4*)(pb + 0 * 2048))[0];
        const float4 p01 = ((const float4*)(pb + 0 * 2048))[1];
        const float4 p10 = ((const float4*)(pb + 1 * 2048))[0];
        const float4 p11 = ((const float4*)(pb + 1 * 2048))[1];
        const float4 p20 = ((const float4*)(pb + 2 * 2048))[0];
        const float4 p21 = ((const float4*)(pb + 2 * 2048))[1];
        const float4 p30 = ((const float4*)(pb + 3 * 2048))[0];
        const float4 p31 = ((const float4*)(pb + 3 * 2048))[1];
        const float4 ba = ((const float4*)(b1 + g * 8))[0];
        const float4 bb = ((const float4*)(b1 + g * 8))[1];
        float* h1w = lds_h1 + el * H1LD + g * 8;
        h1w[0] = ssp(p00.x + p10.x + p20.x + p30.x + ba.x);
        h1w[1] = ssp(p00.y + p10.y + p20.y + p30.y + ba.y);
        h1w[2] = ssp(p00.z + p10.z + p20.z + p30.z + ba.z);
        h1w[3] = ssp(p00.w + p10.w + p20.w + p30.w + ba.w);
        h1w[4] = ssp(p01.x + p11.x + p21.x + p31.x + bb.x);
        h1w[5] = ssp(p01.y + p11.y + p21.y + p31.y + bb.y);
        h1w[6] = ssp(p01.z + p11.z + p21.z + p31.z + bb.z);
        h1w[7] = ssp(p01.w + p11.w + p21.w + p31.w + bb.w);
    }

    // asy partial: this thread's 8 el-nuc pairs (needs only lds_rs)
    float asy = 0.0f;
    __syncthreads();   // rs + W2 staged AND h1 visible
    {
        const float* myrs = lds_rs + el * (N_EL * 3);
        const float4 ch = *(const float4*)charges;
#pragma unroll
        for (int i = 0; i < 8; ++i) {
            const int p = g + 8 * i;
            const int e = p >> 2, n = p & 3;
            const float dx = myrs[e * 3 + 0] - coords[n * 3 + 0];
            const float dy = myrs[e * 3 + 1] - coords[n * 3 + 1];
            const float dz = myrs[e * 3 + 2] - coords[n * 3 + 2];
            const float d = sqrtf(dx * dx + dy * dy + dz * dz);
            const float Z = (n < 2) ? ((n == 0) ? ch.x : ch.y)
                                    : ((n == 2) ? ch.z : ch.w);
            asy += (Z * d + d * d) / (1.0f + d);   // decay = sqrt(2*0.5) = 1
        }
    }
    asy = redg(asy);

    // layers 2/3 (W2 from LDS)
    const float4* __restrict__ W2v = (const float4*)lds_w2;
    const float4* __restrict__ b2v = (const float4*)b2;
    const int wbi = g * 2;
    const float4 b2a = b2v[wbi], b2b = b2v[wbi + 1];
    float s0 = b2a.x, s1 = b2a.y, s2 = b2a.z, s3 = b2a.w;
    float s4 = b2b.x, s5 = b2b.y, s6 = b2b.z, s7 = b2b.w;

    const float* __restrict__ h1row = lds_h1 + el * H1LD;
    for (int k = 0; k < HIDDEN; ++k) {
        const float hk  = h1row[k];
        const float4 wa = W2v[k * 16 + wbi];
        const float4 wb = W2v[k * 16 + wbi + 1];
        s0 = fmaf(hk, wa.x, s0); s1 = fmaf(hk, wa.y, s1);
        s2 = fmaf(hk, wa.z, s2); s3 = fmaf(hk, wa.w, s3);
        s4 = fmaf(hk, wb.x, s4); s5 = fmaf(hk, wb.y, s5);
        s6 = fmaf(hk, wb.z, s6); s7 = fmaf(hk, wb.w, s7);
    }

    const float4* __restrict__ W3v = (const float4*)W3;
    const float4 w3a = W3v[wbi], w3b = W3v[wbi + 1];
    float part = ssp(s0) * w3a.x + ssp(s1) * w3a.y
               + ssp(s2) * w3a.z + ssp(s3) * w3a.w
               + ssp(s4) * w3b.x + ssp(s5) * w3b.y
               + ssp(s6) * w3b.z + ssp(s7) * w3b.w;
    part = redg(part);

    if (g == 0) {
        const float ys = part + b3[0];
        out[b] = __expf(ys) * __expf(-asy);
    }
}

extern "C" void kernel_launch(void* const* d_in, const int* in_sizes, int n_in,
                              void* d_out, int out_size, void* d_ws, size_t ws_size,
                              hipStream_t stream) {
    const float* rs      = (const float*)d_in[0];
    const float* coords  = (const float*)d_in[1];
    const float* charges = (const float*)d_in[2];
    const float* W1      = (const float*)d_in[3];
    const float* b1      = (const float*)d_in[4];
    const float* W2      = (const float*)d_in[5];
    const float* b2      = (const float*)d_in[6];
    const float* W3      = (const float*)d_in[7];
    const float* b3      = (const float*)d_in[8];
    float* out = (float*)d_out;

    const int batch = in_sizes[0] / (N_EL * 3);   // 32768
    intx8* w1f8     = (intx8*)d_ws;               // 368 KB fp8 W1
    float* partials = (float*)((char*)d_ws + WS_PART_OFF);  // 32 MB

    prep_w1_kernel<<<N_PAIRS / 2, 256, 0, stream>>>(W1, w1f8);
    wfnet_gemm<<<batch / TB, BLOCK, 0, stream>>>(rs, coords, w1f8, partials);
    wfnet_tail<<<batch / TB, BLOCK, 0, stream>>>(rs, coords, charges, partials,
                                                 b1, W2, b2, W3, b3, out);
}